// Round 6
// baseline (255.362 us; speedup 1.0000x reference)
//
#include <hip/hip_runtime.h>

typedef short bfrag8 __attribute__((ext_vector_type(8)));
typedef float floatx4 __attribute__((ext_vector_type(4)));

#define MFMA_BF16(a, b, c) __builtin_amdgcn_mfma_f32_16x16x32_bf16((a), (b), (c), 0, 0, 0)

#define S_LEN 2048
#define D_MODEL 1024
#define NH 16
#define DK 64

__device__ __forceinline__ unsigned short f2bf(float f) {
  unsigned int u = __float_as_uint(f);
  u += 0x7fffu + ((u >> 16) & 1u);
  return (unsigned short)(u >> 16);
}

typedef const __attribute__((address_space(1))) unsigned int guint;
typedef __attribute__((address_space(3))) unsigned int luint;
__device__ __forceinline__ void gload16(const void* g, void* l) {
  __builtin_amdgcn_global_load_lds((guint*)g, (luint*)l, 16, 0, 0);
}

// ---------------- all f32 -> bf16 conversions in ONE launch ----------------
// regions (in 1024-elt blocks): x 4096 | mask 4096 | wq wk wv wfc 1024 each
__global__ __launch_bounds__(256) void cvt_all(
    const float* __restrict__ x, const float* __restrict__ mask,
    const float* __restrict__ wq, const float* __restrict__ wk,
    const float* __restrict__ wv, const float* __restrict__ wfc,
    unsigned short* __restrict__ xb, unsigned short* __restrict__ maskb,
    unsigned short* __restrict__ wqb, unsigned short* __restrict__ wkb,
    unsigned short* __restrict__ wvb, unsigned short* __restrict__ wfb) {
  const int bid = blockIdx.x;
  const float* src;
  unsigned short* dst;
  int base;
  if (bid < 4096) { src = x; dst = xb; base = bid; }
  else if (bid < 8192) { src = mask; dst = maskb; base = bid - 4096; }
  else if (bid < 9216) { src = wq; dst = wqb; base = bid - 8192; }
  else if (bid < 10240) { src = wk; dst = wkb; base = bid - 9216; }
  else if (bid < 11264) { src = wv; dst = wvb; base = bid - 10240; }
  else { src = wfc; dst = wfb; base = bid - 11264; }
  const int i = (base * 256 + threadIdx.x) * 4;
  float4 v = *reinterpret_cast<const float4*>(src + i);
  uint2 p;
  p.x = (unsigned int)f2bf(v.x) | ((unsigned int)f2bf(v.y) << 16);
  p.y = (unsigned int)f2bf(v.z) | ((unsigned int)f2bf(v.w) << 16);
  *reinterpret_cast<uint2*>(dst + i) = p;
}

// ---------------- NT GEMM: C[M,N] = A[M,K] * B[N,K]^T (+bias) ----------------
template <int WF32, int TN>
__global__ __launch_bounds__(256) void gemm_nt(
    const unsigned short* __restrict__ A, const unsigned short* __restrict__ B0,
    const unsigned short* __restrict__ B1, const unsigned short* __restrict__ B2,
    unsigned short* __restrict__ C0, unsigned short* __restrict__ C1,
    unsigned short* __restrict__ C2, float* __restrict__ Cf,
    const float* __restrict__ bias) {
  constexpr int K = 1024;
  constexpr int NJ = TN / 32;  // per-wave N fragments
  __shared__ unsigned short As[2][128 * 32];
  __shared__ unsigned short Bs[2][TN * 32];
  const int z = blockIdx.z;
  const unsigned short* Bw = (z == 0) ? B0 : (z == 1) ? B1 : B2;
  unsigned short* Cb = (z == 0) ? C0 : (z == 1) ? C1 : C2;
  const int tid = threadIdx.x, lane = tid & 63, wid = tid >> 6;
  const int lr = lane & 15, lk = lane >> 4;
  const int bm = blockIdx.y * 128, bn = blockIdx.x * TN;
  const int wm = (wid >> 1) * 64, wn = (wid & 1) * (TN / 2);
  floatx4 acc[4][NJ] = {};

  const int srow = tid >> 2, scb = (tid & 3) * 16;
  const int ssw = scb ^ (((srow >> 1) & 3) << 4);  // pre-swizzled source col
  const char* gA = (const char*)A + ((size_t)(bm + srow) * K) * 2 + ssw;
  const char* gB = (const char*)Bw + ((size_t)(bn + srow) * K) * 2 + ssw;

  auto stage = [&](int buf, int k0) {
    gload16(gA + (size_t)k0 * 2, (char*)&As[buf][0] + tid * 16);
    gload16(gA + ((size_t)64 * K + k0) * 2, (char*)&As[buf][0] + 4096 + tid * 16);
    gload16(gB + (size_t)k0 * 2, (char*)&Bs[buf][0] + tid * 16);
    if constexpr (TN == 128)
      gload16(gB + ((size_t)64 * K + k0) * 2, (char*)&Bs[buf][0] + 4096 + tid * 16);
  };

  stage(0, 0);
  __syncthreads();
  int cur = 0;
  const int csw = (lk * 16) ^ (((lr >> 1) & 3) << 4);  // read-side swizzle
  for (int k0 = 0; k0 < K; k0 += 32) {
    if (k0 + 32 < K) stage(cur ^ 1, k0 + 32);
    const char* Ab = (const char*)&As[cur][0];
    const char* Bb = (const char*)&Bs[cur][0];
    bfrag8 af[4], bfr[NJ];
#pragma unroll
    for (int i = 0; i < 4; ++i)
      af[i] = *reinterpret_cast<const bfrag8*>(Ab + (wm + i * 16 + lr) * 64 + csw);
#pragma unroll
    for (int j = 0; j < NJ; ++j)
      bfr[j] = *reinterpret_cast<const bfrag8*>(Bb + (wn + j * 16 + lr) * 64 + csw);
#pragma unroll
    for (int i = 0; i < 4; ++i)
#pragma unroll
      for (int j = 0; j < NJ; ++j)
        acc[i][j] = MFMA_BF16(af[i], bfr[j], acc[i][j]);
    __syncthreads();
    cur ^= 1;
  }

#pragma unroll
  for (int i = 0; i < 4; ++i)
#pragma unroll
    for (int j = 0; j < NJ; ++j) {
      const int row = bm + wm + i * 16 + lk * 4;
      const int col = bn + wn + j * 16 + lr;
#pragma unroll
      for (int r = 0; r < 4; ++r) {
        if (WF32)
          Cf[(size_t)(row + r) * D_MODEL + col] = acc[i][j][r] + bias[col];
        else
          Cb[(size_t)(row + r) * D_MODEL + col] = f2bf(acc[i][j][r]);
      }
    }
}

// ---------------- transpose V: [B*S, D] -> Vt[bh][dk][S] ----------------
__global__ __launch_bounds__(256) void transpose_v(
    const unsigned short* __restrict__ V, unsigned short* __restrict__ Vt) {
  __shared__ unsigned short T[64 * 72];
  const int tid = threadIdx.x;
  const int bh = blockIdx.y, s0 = blockIdx.x * 64;
  const int b = bh >> 4, h = bh & 15;
  const unsigned short* src = V + ((size_t)(b * S_LEN + s0)) * D_MODEL + h * DK;
#pragma unroll
  for (int it = 0; it < 2; ++it) {
    int rr = it * 32 + (tid >> 3);
    int cc = (tid & 7) * 8;
    int sw = cc ^ (((rr >> 3) & 7) * 8);
    *reinterpret_cast<uint4*>(&T[rr * 72 + sw]) =
        *reinterpret_cast<const uint4*>(src + (size_t)rr * D_MODEL + cc);
  }
  __syncthreads();
#pragma unroll
  for (int it = 0; it < 2; ++it) {
    int chunk = it * 256 + tid;
    int d = chunk >> 3, sc = chunk & 7;
    unsigned short v[8];
#pragma unroll
    for (int i = 0; i < 8; ++i) {
      int row = sc * 8 + i;
      int col = ((d & ~7) ^ (((row >> 3) & 7) * 8)) + (d & 7);
      v[i] = T[row * 72 + col];
    }
    uint4 pk;
    pk.x = (unsigned int)v[0] | ((unsigned int)v[1] << 16);
    pk.y = (unsigned int)v[2] | ((unsigned int)v[3] << 16);
    pk.z = (unsigned int)v[4] | ((unsigned int)v[5] << 16);
    pk.w = (unsigned int)v[6] | ((unsigned int)v[7] << 16);
    *reinterpret_cast<uint4*>(&Vt[((size_t)bh * DK + d) * S_LEN + s0 + sc * 8]) = pk;
  }
}

// ---------------- fused relu-attention (V direct-from-L2, K 3-buffered) ------
// Block = one (b,h) x 64 q rows; 4 waves x 16 q; 1024 blocks (4/CU).
// V fragments load straight global(L2)->registers at iteration top (no V LDS).
// K tile triple-buffered in LDS, staged 2 tiles ahead via global_load_lds;
// the compiler's own vmcnt wait for the (newer) mask registers retires the
// K-stage of tile kt+1 before the bare s_barrier -> barrier never waits on
// memory. LDS traffic/wave-iter: 12 KB (was 20). bf16 mask.
__global__ __launch_bounds__(256, 4) void attn_relu(
    const unsigned short* __restrict__ Q, const unsigned short* __restrict__ Kg,
    const unsigned short* __restrict__ Vt, const unsigned short* __restrict__ Mb,
    unsigned short* __restrict__ O) {
  __shared__ unsigned short Kt[3][64 * 64];  // [k][d] 24 KB, 3-buffered
  __shared__ unsigned short Pw[4][16 * 64];  // per-wave [q16][k64] 8 KB
  const int tid = threadIdx.x, lane = tid & 63, wid = tid >> 6;
  const int lr = lane & 15, lk = lane >> 4;
  // XCD-aware swizzle over 1024 blocks: each XCD gets 128 consecutive flats
  // = 4 bh worth of K/V -> L2 locality. 1024 % 8 == 0 (bijective).
  int flat = blockIdx.y * 32 + blockIdx.x;
  flat = (flat & 7) * 128 + (flat >> 3);
  const int bh = flat >> 5, q0 = (flat & 31) * 64;
  const int b = bh >> 4, h = bh & 15;
  const int q = q0 + wid * 16 + lr;

  // Q B-fragments straight from global
  const unsigned short* qptr = Q + (size_t)(b * S_LEN + q) * D_MODEL + h * DK;
  bfrag8 qf[2];
#pragma unroll
  for (int ks = 0; ks < 2; ++ks)
    qf[ks] = *reinterpret_cast<const bfrag8*>(qptr + ks * 32 + lk * 8);

  // K staging: thread t -> LDS row p*32 + (t>>3), 16B chunk (t&7); src pre-swz
  const int srow = tid >> 3, scb = (tid & 7) * 16;
  const int ssw = scb ^ ((srow & 7) << 4);
  const char* kg = (const char*)Kg + ((size_t)(b * S_LEN + srow)) * 2048 + h * 128 + ssw;
  // V direct: this lane's fragment rows: d = dj*16 + lr, s-chunk = lk*8
  const unsigned short* vptr =
      Vt + (size_t)bh * DK * S_LEN + (size_t)lr * S_LEN + lk * 8;
  const unsigned short* mrow = Mb + (size_t)q * S_LEN + lk * 4;

  floatx4 oacc[4] = {};

  auto stageK = [&](int buf, int kt) {
#pragma unroll
    for (int p = 0; p < 2; ++p)
      gload16(kg + (size_t)(kt * 64 + p * 32) * 2048,
              (char*)&Kt[buf][0] + p * 4096 + tid * 16);
  };

  // prologue: stage K tiles 0 and 1 (full drain once)
  stageK(0, 0);
  stageK(1, 1);
  __syncthreads();

  int cur = 0;
  const int swzq = (lr & 7) << 4;
  char* PwW = (char*)&Pw[wid][0] + lr * 128;
  constexpr int NT = S_LEN / 64;
  for (int kt = 0; kt < NT; ++kt) {
    // ---- issue all vmem up front, oldest -> newest:
    // (1) V fragments for THIS tile (consumed in PV, ~500cy away)
    bfrag8 vb[2][4];
#pragma unroll
    for (int kk = 0; kk < 2; ++kk)
#pragma unroll
      for (int dj = 0; dj < 4; ++dj)
        vb[kk][dj] = *reinterpret_cast<const bfrag8*>(
            vptr + (size_t)(dj * 16) * S_LEN + kt * 64 + kk * 32);
    __builtin_amdgcn_sched_barrier(0);
    // (2) mask for THIS tile (consumed in epilogue; its wait retires K(kt+1))
    uint2 mreg[4];
#pragma unroll
    for (int ni = 0; ni < 4; ++ni)
      mreg[ni] = *reinterpret_cast<const uint2*>(mrow + kt * 64 + ni * 16);
    __builtin_amdgcn_sched_barrier(0);
    // (3) K stage 2 tiles ahead (newest; survives all this iter's reg waits)
    int nb = cur + 2; if (nb >= 3) nb -= 3;
    if (kt + 2 < NT) stageK(nb, kt + 2);
    __builtin_amdgcn_sched_barrier(0);

    // ---- scores (transposed): sacc[ni] rows k, cols q
    const char* Kb = (const char*)&Kt[cur][0];
    floatx4 sacc[4] = {};
    __builtin_amdgcn_s_setprio(1);
#pragma unroll
    for (int ks = 0; ks < 2; ++ks) {
      bfrag8 kf[4];
#pragma unroll
      for (int ni = 0; ni < 4; ++ni)
        kf[ni] = *reinterpret_cast<const bfrag8*>(
            Kb + (ni * 16 + lr) * 128 + ((ks * 64 + lk * 16) ^ swzq));
#pragma unroll
      for (int ni = 0; ni < 4; ++ni)
        sacc[ni] = MFMA_BF16(kf[ni], qf[ks], sacc[ni]);
    }
    __builtin_amdgcn_s_setprio(0);

    // ---- relu(scale*s + mask) -> bf16 -> wave-private swizzled P strip
#pragma unroll
    for (int ni = 0; ni < 4; ++ni) {
      float m0 = __uint_as_float((mreg[ni].x & 0xffffu) << 16);
      float m1 = __uint_as_float(mreg[ni].x & 0xffff0000u);
      float m2 = __uint_as_float((mreg[ni].y & 0xffffu) << 16);
      float m3 = __uint_as_float(mreg[ni].y & 0xffff0000u);
      float p0 = fmaxf(fmaf(sacc[ni][0], 0.125f, m0), 0.f);
      float p1 = fmaxf(fmaf(sacc[ni][1], 0.125f, m1), 0.f);
      float p2 = fmaxf(fmaf(sacc[ni][2], 0.125f, m2), 0.f);
      float p3 = fmaxf(fmaf(sacc[ni][3], 0.125f, m3), 0.f);
      uint2 pk;
      asm("v_cvt_pk_bf16_f32 %0, %1, %2" : "=v"(pk.x) : "v"(p0), "v"(p1));
      asm("v_cvt_pk_bf16_f32 %0, %1, %2" : "=v"(pk.y) : "v"(p2), "v"(p3));
      *reinterpret_cast<uint2*>(PwW + ((ni * 32 + lk * 8) ^ swzq)) = pk;
    }
    asm volatile("s_waitcnt lgkmcnt(0)" ::: "memory");
    __builtin_amdgcn_sched_barrier(0);  // rule 18: keep MFMA below the wait

    // ---- PV: O^T += mfma(A = V^T frag (regs), B = P^T frag)
    __builtin_amdgcn_s_setprio(1);
#pragma unroll
    for (int kk = 0; kk < 2; ++kk) {
      const int cV = (kk * 64 + lk * 16) ^ swzq;
      bfrag8 pB = *reinterpret_cast<const bfrag8*>(PwW + cV);
#pragma unroll
      for (int dj = 0; dj < 4; ++dj)
        oacc[dj] = MFMA_BF16(vb[kk][dj], pB, oacc[dj]);
    }
    __builtin_amdgcn_s_setprio(0);

    // ---- bare barrier: gates Kt[(kt+1)%3] reads; K(kt+1) already retired by
    // this iter's mask-register wait (vmcnt FIFO), so no memory wait here.
    __builtin_amdgcn_sched_barrier(0);
    __builtin_amdgcn_s_barrier();
    __builtin_amdgcn_sched_barrier(0);
    cur = (cur + 1 == 3) ? 0 : cur + 1;
  }

  // ---- write O (bf16, [B*S][D]); O^T frag: row d = dj*16+4*lk+r, col q
  const size_t orow = (size_t)(b * S_LEN + q) * D_MODEL + h * DK + lk * 4;
#pragma unroll
  for (int dj = 0; dj < 4; ++dj) {
    uint2 pk;
    pk.x = (unsigned int)f2bf(oacc[dj][0]) | ((unsigned int)f2bf(oacc[dj][1]) << 16);
    pk.y = (unsigned int)f2bf(oacc[dj][2]) | ((unsigned int)f2bf(oacc[dj][3]) << 16);
    *reinterpret_cast<uint2*>(&O[orow + dj * 16]) = pk;
  }
}

extern "C" void kernel_launch(void* const* d_in, const int* in_sizes, int n_in,
                              void* d_out, int out_size, void* d_ws, size_t ws_size,
                              hipStream_t stream) {
  const float* x = (const float*)d_in[0];
  const float* mask = (const float*)d_in[1];
  const float* Wq = (const float*)d_in[2];
  const float* Wk = (const float*)d_in[3];
  const float* Wv = (const float*)d_in[4];
  const float* Wfc = (const float*)d_in[5];
  const float* bfc = (const float*)d_in[6];
  float* out = (float*)d_out;

  char* ws = (char*)d_ws;
  const size_t MB = 1u << 20;
  unsigned short* xb = (unsigned short*)(ws + 0 * MB);     // 8 MB (reused as Ow)
  unsigned short* Wqb = (unsigned short*)(ws + 8 * MB);    // 2 MB
  unsigned short* Wkb = (unsigned short*)(ws + 10 * MB);   // 2 MB
  unsigned short* Wvb = (unsigned short*)(ws + 12 * MB);   // 2 MB
  unsigned short* Wfb = (unsigned short*)(ws + 14 * MB);   // 2 MB
  unsigned short* Qw = (unsigned short*)(ws + 16 * MB);    // 8 MB
  unsigned short* Kw = (unsigned short*)(ws + 24 * MB);    // 8 MB
  unsigned short* Vw = (unsigned short*)(ws + 32 * MB);    // 8 MB
  unsigned short* Vtw = (unsigned short*)(ws + 40 * MB);   // 8 MB
  unsigned short* maskb = (unsigned short*)(ws + 48 * MB); // 8 MB
  unsigned short* Ow = xb;  // attn runs after QKV GEMMs; xb is dead by then

  cvt_all<<<12288, 256, 0, stream>>>(x, mask, Wq, Wk, Wv, Wfc,
                                     xb, maskb, Wqb, Wkb, Wvb, Wfb);

  // merged Q/K/V projection: one launch, z selects weight/output
  gemm_nt<0, 128><<<dim3(D_MODEL / 128, (2 * S_LEN) / 128, 3), 256, 0, stream>>>(
      xb, Wqb, Wkb, Wvb, Qw, Kw, Vw, nullptr, nullptr);

  transpose_v<<<dim3(S_LEN / 64, 32), 256, 0, stream>>>(Vw, Vtw);

  attn_relu<<<dim3(S_LEN / 64, 32), 256, 0, stream>>>(Qw, Kw, Vtw, maskb, Ow);

  // FC: 128x64 tiles -> 512 blocks (2/CU) for latency hiding
  gemm_nt<1, 64><<<dim3(D_MODEL / 64, (2 * S_LEN) / 128, 1), 256, 0, stream>>>(
      Ow, Wfb, nullptr, nullptr, nullptr, nullptr, nullptr, out, bfc);
}

// Round 7
// 142.745 us; speedup vs baseline: 1.7889x; 1.7889x over previous
//
#include <hip/hip_runtime.h>

typedef short bfrag8 __attribute__((ext_vector_type(8)));
typedef float floatx4 __attribute__((ext_vector_type(4)));
typedef float floatx16 __attribute__((ext_vector_type(16)));

#define MFMA_BF16(a, b, c) __builtin_amdgcn_mfma_f32_16x16x32_bf16((a), (b), (c), 0, 0, 0)
#define MFMA32(a, b, c) __builtin_amdgcn_mfma_f32_32x32x16_bf16((a), (b), (c), 0, 0, 0)

#define S_LEN 2048
#define D_MODEL 1024
#define NH 16
#define DK 64

__device__ __forceinline__ unsigned short f2bf(float f) {
  unsigned int u = __float_as_uint(f);
  u += 0x7fffu + ((u >> 16) & 1u);
  return (unsigned short)(u >> 16);
}

typedef const __attribute__((address_space(1))) unsigned int guint;
typedef __attribute__((address_space(3))) unsigned int luint;
__device__ __forceinline__ void gload16(const void* g, void* l) {
  __builtin_amdgcn_global_load_lds((guint*)g, (luint*)l, 16, 0, 0);
}

// ---------------- all f32 -> bf16 conversions in ONE launch ----------------
// regions (in 1024-elt blocks): x 4096 | mask 4096 | wq wk wv wfc 1024 each
__global__ __launch_bounds__(256) void cvt_all(
    const float* __restrict__ x, const float* __restrict__ mask,
    const float* __restrict__ wq, const float* __restrict__ wk,
    const float* __restrict__ wv, const float* __restrict__ wfc,
    unsigned short* __restrict__ xb, unsigned short* __restrict__ maskb,
    unsigned short* __restrict__ wqb, unsigned short* __restrict__ wkb,
    unsigned short* __restrict__ wvb, unsigned short* __restrict__ wfb) {
  const int bid = blockIdx.x;
  const float* src;
  unsigned short* dst;
  int base;
  if (bid < 4096) { src = x; dst = xb; base = bid; }
  else if (bid < 8192) { src = mask; dst = maskb; base = bid - 4096; }
  else if (bid < 9216) { src = wq; dst = wqb; base = bid - 8192; }
  else if (bid < 10240) { src = wk; dst = wkb; base = bid - 9216; }
  else if (bid < 11264) { src = wv; dst = wvb; base = bid - 10240; }
  else { src = wfc; dst = wfb; base = bid - 11264; }
  const int i = (base * 256 + threadIdx.x) * 4;
  float4 v = *reinterpret_cast<const float4*>(src + i);
  uint2 p;
  p.x = (unsigned int)f2bf(v.x) | ((unsigned int)f2bf(v.y) << 16);
  p.y = (unsigned int)f2bf(v.z) | ((unsigned int)f2bf(v.w) << 16);
  *reinterpret_cast<uint2*>(dst + i) = p;
}

// ---------------- NT GEMM: C[M,N] = A[M,K] * B[N,K]^T (+bias) ----------------
template <int WF32, int TN>
__global__ __launch_bounds__(256) void gemm_nt(
    const unsigned short* __restrict__ A, const unsigned short* __restrict__ B0,
    const unsigned short* __restrict__ B1, const unsigned short* __restrict__ B2,
    unsigned short* __restrict__ C0, unsigned short* __restrict__ C1,
    unsigned short* __restrict__ C2, float* __restrict__ Cf,
    const float* __restrict__ bias) {
  constexpr int K = 1024;
  constexpr int NJ = TN / 32;  // per-wave N fragments
  __shared__ unsigned short As[2][128 * 32];
  __shared__ unsigned short Bs[2][TN * 32];
  const int z = blockIdx.z;
  const unsigned short* Bw = (z == 0) ? B0 : (z == 1) ? B1 : B2;
  unsigned short* Cb = (z == 0) ? C0 : (z == 1) ? C1 : C2;
  const int tid = threadIdx.x, lane = tid & 63, wid = tid >> 6;
  const int lr = lane & 15, lk = lane >> 4;
  const int bm = blockIdx.y * 128, bn = blockIdx.x * TN;
  const int wm = (wid >> 1) * 64, wn = (wid & 1) * (TN / 2);
  floatx4 acc[4][NJ] = {};

  const int srow = tid >> 2, scb = (tid & 3) * 16;
  const int ssw = scb ^ (((srow >> 1) & 3) << 4);  // pre-swizzled source col
  const char* gA = (const char*)A + ((size_t)(bm + srow) * K) * 2 + ssw;
  const char* gB = (const char*)Bw + ((size_t)(bn + srow) * K) * 2 + ssw;

  auto stage = [&](int buf, int k0) {
    gload16(gA + (size_t)k0 * 2, (char*)&As[buf][0] + tid * 16);
    gload16(gA + ((size_t)64 * K + k0) * 2, (char*)&As[buf][0] + 4096 + tid * 16);
    gload16(gB + (size_t)k0 * 2, (char*)&Bs[buf][0] + tid * 16);
    if constexpr (TN == 128)
      gload16(gB + ((size_t)64 * K + k0) * 2, (char*)&Bs[buf][0] + 4096 + tid * 16);
  };

  stage(0, 0);
  __syncthreads();
  int cur = 0;
  const int csw = (lk * 16) ^ (((lr >> 1) & 3) << 4);  // read-side swizzle
  for (int k0 = 0; k0 < K; k0 += 32) {
    if (k0 + 32 < K) stage(cur ^ 1, k0 + 32);
    const char* Ab = (const char*)&As[cur][0];
    const char* Bb = (const char*)&Bs[cur][0];
    bfrag8 af[4], bfr[NJ];
#pragma unroll
    for (int i = 0; i < 4; ++i)
      af[i] = *reinterpret_cast<const bfrag8*>(Ab + (wm + i * 16 + lr) * 64 + csw);
#pragma unroll
    for (int j = 0; j < NJ; ++j)
      bfr[j] = *reinterpret_cast<const bfrag8*>(Bb + (wn + j * 16 + lr) * 64 + csw);
#pragma unroll
    for (int i = 0; i < 4; ++i)
#pragma unroll
      for (int j = 0; j < NJ; ++j)
        acc[i][j] = MFMA_BF16(af[i], bfr[j], acc[i][j]);
    __syncthreads();
    cur ^= 1;
  }

#pragma unroll
  for (int i = 0; i < 4; ++i)
#pragma unroll
    for (int j = 0; j < NJ; ++j) {
      const int row = bm + wm + i * 16 + lk * 4;
      const int col = bn + wn + j * 16 + lr;
#pragma unroll
      for (int r = 0; r < 4; ++r) {
        if (WF32)
          Cf[(size_t)(row + r) * D_MODEL + col] = acc[i][j][r] + bias[col];
        else
          Cb[(size_t)(row + r) * D_MODEL + col] = f2bf(acc[i][j][r]);
      }
    }
}

// ---------------- transpose V: [B*S, D] -> Vt[bh][dk][S] ----------------
__global__ __launch_bounds__(256) void transpose_v(
    const unsigned short* __restrict__ V, unsigned short* __restrict__ Vt) {
  __shared__ unsigned short T[64 * 72];
  const int tid = threadIdx.x;
  const int bh = blockIdx.y, s0 = blockIdx.x * 64;
  const int b = bh >> 4, h = bh & 15;
  const unsigned short* src = V + ((size_t)(b * S_LEN + s0)) * D_MODEL + h * DK;
#pragma unroll
  for (int it = 0; it < 2; ++it) {
    int rr = it * 32 + (tid >> 3);
    int cc = (tid & 7) * 8;
    int sw = cc ^ (((rr >> 3) & 7) * 8);
    *reinterpret_cast<uint4*>(&T[rr * 72 + sw]) =
        *reinterpret_cast<const uint4*>(src + (size_t)rr * D_MODEL + cc);
  }
  __syncthreads();
#pragma unroll
  for (int it = 0; it < 2; ++it) {
    int chunk = it * 256 + tid;
    int d = chunk >> 3, sc = chunk & 7;
    unsigned short v[8];
#pragma unroll
    for (int i = 0; i < 8; ++i) {
      int row = sc * 8 + i;
      int col = ((d & ~7) ^ (((row >> 3) & 7) * 8)) + (d & 7);
      v[i] = T[row * 72 + col];
    }
    uint4 pk;
    pk.x = (unsigned int)v[0] | ((unsigned int)v[1] << 16);
    pk.y = (unsigned int)v[2] | ((unsigned int)v[3] << 16);
    pk.z = (unsigned int)v[4] | ((unsigned int)v[5] << 16);
    pk.w = (unsigned int)v[6] | ((unsigned int)v[7] << 16);
    *reinterpret_cast<uint4*>(&Vt[((size_t)bh * DK + d) * S_LEN + s0 + sc * 8]) = pk;
  }
}

// ---------------- fused relu-attention (32x32 MFMA, in-register P) -----------
// Block = one (b,h) x 128 q; 4 waves x 32 q; grid 512 (2 blocks/CU).
// S^T = mfma32(K,Q): lane holds col q=lane&31, 16 k-rows (reg&3)+8(reg>>2)+4h.
// P never touches LDS: scale+mask+relu in f32 regs, v_cvt_pk_bf16_f32 pairs,
// v_permlane32_swap_b32 exchanges the h=0/h=1 halves to build PV B-fragments.
// O^T = mfma32(V^T, P^T). K/V double-buffered via global_load_lds with
// two-level XOR swizzle ((r&7)<<4)^(((r>>3)&1)<<5) -> worst 2-way conflict.
__global__ __launch_bounds__(256, 2) void attn_relu(
    const unsigned short* __restrict__ Q, const unsigned short* __restrict__ Kg,
    const unsigned short* __restrict__ Vt, const unsigned short* __restrict__ Mb,
    unsigned short* __restrict__ O) {
  __shared__ unsigned short Kt[2][64 * 64];  // [k][d] 16 KB
  __shared__ unsigned short Vl[2][64 * 64];  // [d][s] 16 KB
  const int tid = threadIdx.x, lane = tid & 63, wid = tid >> 6;
  const int lq = lane & 31, hf = lane >> 5;
  // XCD-aware swizzle over 512 blocks: 64 consecutive flats (4 bh) per XCD.
  int flat = blockIdx.y * 16 + blockIdx.x;
  flat = (flat & 7) * 64 + (flat >> 3);
  const int bh = flat >> 4, q0 = (flat & 15) * 128;
  const int b = bh >> 4, hh = bh & 15;
  const int qg = q0 + wid * 32 + lq;  // this lane's q row

  // Q B-fragments (col=q, k-elems d = ks*16 + hf*8 + i), straight from global
  const unsigned short* qptr = Q + (size_t)(b * S_LEN + qg) * D_MODEL + hh * DK;
  bfrag8 qf[4];
#pragma unroll
  for (int ks = 0; ks < 4; ++ks)
    qf[ks] = *reinterpret_cast<const bfrag8*>(qptr + ks * 16 + hf * 8);

  // staging: thread t -> LDS row (t>>3) + 32p, 16B chunk (t&7); src pre-swz
  const int srow = tid >> 3, scb = (tid & 7) * 16;
  const int ssw = scb ^ ((srow & 7) << 4) ^ (((srow >> 3) & 1) << 5);
  const char* kg = (const char*)Kg + ((size_t)(b * S_LEN + srow)) * 2048 + hh * 128 + ssw;
  const char* vg = (const char*)Vt + (size_t)bh * (DK * S_LEN * 2) +
                   (size_t)srow * (S_LEN * 2) + ssw;
  const unsigned short* mrow = Mb + (size_t)qg * S_LEN;
  const int swzr = ((lq & 7) << 4) ^ (((lq >> 3) & 1) << 5);  // read-side

  floatx16 oacc[2] = {};

  auto stage = [&](int buf, int kt) {
#pragma unroll
    for (int p = 0; p < 2; ++p) {
      gload16(kg + (size_t)(kt * 64 + p * 32) * 2048,
              (char*)&Kt[buf][0] + p * 4096 + tid * 16);
      gload16(vg + (size_t)(p * 32) * 4096 + (size_t)kt * 128,
              (char*)&Vl[buf][0] + p * 4096 + tid * 16);
    }
  };

  stage(0, 0);
  __syncthreads();

  int cur = 0;
  constexpr int NT = S_LEN / 64;
  for (int kt = 0; kt < NT; ++kt) {
    if (kt + 1 < NT) stage(cur ^ 1, kt + 1);
    // mask: 4 bf16 per (kblk, reg-group); rows k = kt*64+c*32+8g+4hf+{0..3}
    uint2 mk[2][4];
#pragma unroll
    for (int c = 0; c < 2; ++c)
#pragma unroll
      for (int g = 0; g < 4; ++g)
        mk[c][g] = *reinterpret_cast<const uint2*>(
            mrow + kt * 64 + c * 32 + 8 * g + 4 * hf);

    // ---- scores: sacc[c] = S^T (32k x 32q), c = k-block
    const char* Kb = (const char*)&Kt[cur][0];
    floatx16 sacc[2] = {};
    __builtin_amdgcn_s_setprio(1);
#pragma unroll
    for (int c = 0; c < 2; ++c)
#pragma unroll
      for (int ks = 0; ks < 4; ++ks) {
        bfrag8 kf = *reinterpret_cast<const bfrag8*>(
            Kb + (c * 32 + lq) * 128 + (((ks * 16 + hf * 8) * 2) ^ swzr));
        sacc[c] = MFMA32(kf, qf[ks], sacc[c]);
      }
    __builtin_amdgcn_s_setprio(0);

    // ---- relu(scale*s + mask) in registers -> bf16 -> permlane32_swap
    bfrag8 pf[4];
#pragma unroll
    for (int c = 0; c < 2; ++c) {
      float p[16];
#pragma unroll
      for (int g = 0; g < 4; ++g) {
        float m0 = __uint_as_float((mk[c][g].x & 0xffffu) << 16);
        float m1 = __uint_as_float(mk[c][g].x & 0xffff0000u);
        float m2 = __uint_as_float((mk[c][g].y & 0xffffu) << 16);
        float m3 = __uint_as_float(mk[c][g].y & 0xffff0000u);
        p[4 * g + 0] = fmaxf(fmaf(sacc[c][4 * g + 0], 0.125f, m0), 0.f);
        p[4 * g + 1] = fmaxf(fmaf(sacc[c][4 * g + 1], 0.125f, m1), 0.f);
        p[4 * g + 2] = fmaxf(fmaf(sacc[c][4 * g + 2], 0.125f, m2), 0.f);
        p[4 * g + 3] = fmaxf(fmaf(sacc[c][4 * g + 3], 0.125f, m3), 0.f);
      }
      unsigned int a0, a1, b0, b1, a2, a3, b2, b3;
      asm("v_cvt_pk_bf16_f32 %0, %1, %2" : "=v"(a0) : "v"(p[0]), "v"(p[1]));
      asm("v_cvt_pk_bf16_f32 %0, %1, %2" : "=v"(a1) : "v"(p[2]), "v"(p[3]));
      asm("v_cvt_pk_bf16_f32 %0, %1, %2" : "=v"(b0) : "v"(p[4]), "v"(p[5]));
      asm("v_cvt_pk_bf16_f32 %0, %1, %2" : "=v"(b1) : "v"(p[6]), "v"(p[7]));
      asm("v_cvt_pk_bf16_f32 %0, %1, %2" : "=v"(a2) : "v"(p[8]), "v"(p[9]));
      asm("v_cvt_pk_bf16_f32 %0, %1, %2" : "=v"(a3) : "v"(p[10]), "v"(p[11]));
      asm("v_cvt_pk_bf16_f32 %0, %1, %2" : "=v"(b2) : "v"(p[12]), "v"(p[13]));
      asm("v_cvt_pk_bf16_f32 %0, %1, %2" : "=v"(b3) : "v"(p[14]), "v"(p[15]));
      // swap h-halves: a' = {a.lo, b.lo}, b' = {a.hi, b.hi}
      asm("v_permlane32_swap_b32 %0, %1" : "+v"(a0), "+v"(b0));
      asm("v_permlane32_swap_b32 %0, %1" : "+v"(a1), "+v"(b1));
      asm("v_permlane32_swap_b32 %0, %1" : "+v"(a2), "+v"(b2));
      asm("v_permlane32_swap_b32 %0, %1" : "+v"(a3), "+v"(b3));
      uint4 u0, u1;
      u0.x = a0; u0.y = a1; u0.z = b0; u0.w = b1;  // k-step c*2+0
      u1.x = a2; u1.y = a3; u1.z = b2; u1.w = b3;  // k-step c*2+1
      pf[c * 2 + 0] = *reinterpret_cast<bfrag8*>(&u0);
      pf[c * 2 + 1] = *reinterpret_cast<bfrag8*>(&u1);
    }

    // ---- PV: O^T += mfma32(A = V^T frag from LDS, B = P^T frag in regs)
    const char* Vb = (const char*)&Vl[cur][0];
    __builtin_amdgcn_s_setprio(1);
#pragma unroll
    for (int d = 0; d < 2; ++d)
#pragma unroll
      for (int s = 0; s < 4; ++s) {
        bfrag8 vb = *reinterpret_cast<const bfrag8*>(
            Vb + (d * 32 + lq) * 128 + (((s * 16 + hf * 8) * 2) ^ swzr));
        oacc[d] = MFMA32(vb, pf[s], oacc[d]);
      }
    __builtin_amdgcn_s_setprio(0);
    __syncthreads();  // prefetch landed; all waves done with cur
    cur ^= 1;
  }

  // ---- write O (bf16, [B*S][D]); O^T row d = dblk*32 + (reg&3)+8g+4hf, col q
  const size_t obase = (size_t)(b * S_LEN + qg) * D_MODEL + hh * DK;
#pragma unroll
  for (int d = 0; d < 2; ++d)
#pragma unroll
    for (int g = 0; g < 4; ++g) {
      uint2 pk;
      pk.x = (unsigned int)f2bf(oacc[d][4 * g + 0]) |
             ((unsigned int)f2bf(oacc[d][4 * g + 1]) << 16);
      pk.y = (unsigned int)f2bf(oacc[d][4 * g + 2]) |
             ((unsigned int)f2bf(oacc[d][4 * g + 3]) << 16);
      *reinterpret_cast<uint2*>(&O[obase + d * 32 + 8 * g + 4 * hf]) = pk;
    }
}

extern "C" void kernel_launch(void* const* d_in, const int* in_sizes, int n_in,
                              void* d_out, int out_size, void* d_ws, size_t ws_size,
                              hipStream_t stream) {
  const float* x = (const float*)d_in[0];
  const float* mask = (const float*)d_in[1];
  const float* Wq = (const float*)d_in[2];
  const float* Wk = (const float*)d_in[3];
  const float* Wv = (const float*)d_in[4];
  const float* Wfc = (const float*)d_in[5];
  const float* bfc = (const float*)d_in[6];
  float* out = (float*)d_out;

  char* ws = (char*)d_ws;
  const size_t MB = 1u << 20;
  unsigned short* xb = (unsigned short*)(ws + 0 * MB);     // 8 MB (reused as Ow)
  unsigned short* Wqb = (unsigned short*)(ws + 8 * MB);    // 2 MB
  unsigned short* Wkb = (unsigned short*)(ws + 10 * MB);   // 2 MB
  unsigned short* Wvb = (unsigned short*)(ws + 12 * MB);   // 2 MB
  unsigned short* Wfb = (unsigned short*)(ws + 14 * MB);   // 2 MB
  unsigned short* Qw = (unsigned short*)(ws + 16 * MB);    // 8 MB
  unsigned short* Kw = (unsigned short*)(ws + 24 * MB);    // 8 MB
  unsigned short* Vw = (unsigned short*)(ws + 32 * MB);    // 8 MB
  unsigned short* Vtw = (unsigned short*)(ws + 40 * MB);   // 8 MB
  unsigned short* maskb = (unsigned short*)(ws + 48 * MB); // 8 MB
  unsigned short* Ow = xb;  // attn runs after QKV GEMMs; xb is dead by then

  cvt_all<<<12288, 256, 0, stream>>>(x, mask, Wq, Wk, Wv, Wfc,
                                     xb, maskb, Wqb, Wkb, Wvb, Wfb);

  // merged Q/K/V projection: one launch, z selects weight/output
  gemm_nt<0, 128><<<dim3(D_MODEL / 128, (2 * S_LEN) / 128, 3), 256, 0, stream>>>(
      xb, Wqb, Wkb, Wvb, Qw, Kw, Vw, nullptr, nullptr);

  transpose_v<<<dim3(S_LEN / 64, 32), 256, 0, stream>>>(Vw, Vtw);

  attn_relu<<<dim3(S_LEN / 128, 32), 256, 0, stream>>>(Qw, Kw, Vtw, maskb, Ow);

  // FC: 128x64 tiles -> 512 blocks (2/CU) for latency hiding
  gemm_nt<1, 64><<<dim3(D_MODEL / 64, (2 * S_LEN) / 128, 1), 256, 0, stream>>>(
      Ow, Wfb, nullptr, nullptr, nullptr, nullptr, nullptr, out, bfc);
}

// Round 8
// 137.434 us; speedup vs baseline: 1.8581x; 1.0386x over previous
//
#include <hip/hip_runtime.h>

typedef short bfrag8 __attribute__((ext_vector_type(8)));
typedef float floatx4 __attribute__((ext_vector_type(4)));
typedef float floatx16 __attribute__((ext_vector_type(16)));

#define MFMA_BF16(a, b, c) __builtin_amdgcn_mfma_f32_16x16x32_bf16((a), (b), (c), 0, 0, 0)
#define MFMA32(a, b, c) __builtin_amdgcn_mfma_f32_32x32x16_bf16((a), (b), (c), 0, 0, 0)

#define S_LEN 2048
#define D_MODEL 1024
#define NH 16
#define DK 64

__device__ __forceinline__ unsigned short f2bf(float f) {
  unsigned int u = __float_as_uint(f);
  u += 0x7fffu + ((u >> 16) & 1u);
  return (unsigned short)(u >> 16);
}

typedef const __attribute__((address_space(1))) unsigned int guint;
typedef __attribute__((address_space(3))) unsigned int luint;
__device__ __forceinline__ void gload16(const void* g, void* l) {
  __builtin_amdgcn_global_load_lds((guint*)g, (luint*)l, 16, 0, 0);
}

// ---------------- f32 -> bf16 conversions (x + 4 weights) ----------------
// regions (in 1024-elt blocks): x 4096 | wq wk wv wfc 1024 each
__global__ __launch_bounds__(256) void cvt_all(
    const float* __restrict__ x, const float* __restrict__ wq,
    const float* __restrict__ wk, const float* __restrict__ wv,
    const float* __restrict__ wfc, unsigned short* __restrict__ xb,
    unsigned short* __restrict__ wqb, unsigned short* __restrict__ wkb,
    unsigned short* __restrict__ wvb, unsigned short* __restrict__ wfb) {
  const int bid = blockIdx.x;
  const float* src;
  unsigned short* dst;
  int base;
  if (bid < 4096) { src = x; dst = xb; base = bid; }
  else if (bid < 5120) { src = wq; dst = wqb; base = bid - 4096; }
  else if (bid < 6144) { src = wk; dst = wkb; base = bid - 5120; }
  else if (bid < 7168) { src = wv; dst = wvb; base = bid - 6144; }
  else { src = wfc; dst = wfb; base = bid - 7168; }
  const int i = (base * 256 + threadIdx.x) * 4;
  float4 v = *reinterpret_cast<const float4*>(src + i);
  uint2 p;
  p.x = (unsigned int)f2bf(v.x) | ((unsigned int)f2bf(v.y) << 16);
  p.y = (unsigned int)f2bf(v.z) | ((unsigned int)f2bf(v.w) << 16);
  *reinterpret_cast<uint2*>(dst + i) = p;
}

// ---------------- pack mask into MFMA-fragment order ----------------
// Mp layout: [g6 = k>>3][hf = (k>>2)&1][q][r = k&3] bf16, so a lane's 4
// k-values (r=0..3) for its (c,g,hf) group are one uint2 at elem offset
// ((g6*2+hf)*2048 + q)*4 -> lanes (consecutive q) read contiguous 8B.
__global__ __launch_bounds__(256) void pack_mask(
    const float* __restrict__ mask, unsigned short* __restrict__ Mp) {
  __shared__ unsigned short T[64 * 132];
  const int tid = threadIdx.x;
  const int kp = blockIdx.x, qp = blockIdx.y;  // 128-k patch, 64-q patch
#pragma unroll
  for (int it = 0; it < 8; ++it) {
    int idx = it * 256 + tid;
    int q = idx >> 5, kq = (idx & 31) * 4;
    float4 v = *reinterpret_cast<const float4*>(
        mask + (size_t)(qp * 64 + q) * 2048 + kp * 128 + kq);
    uint2 p;
    p.x = (unsigned int)f2bf(v.x) | ((unsigned int)f2bf(v.y) << 16);
    p.y = (unsigned int)f2bf(v.z) | ((unsigned int)f2bf(v.w) << 16);
    *reinterpret_cast<uint2*>(&T[q * 132 + kq]) = p;
  }
  __syncthreads();
  const int run = tid >> 3, qb = tid & 7;   // 32 runs x 8 q-lanes
  const int g6l = run >> 1, hf = run & 1;   // local k-group, half
  const int kloc = g6l * 8 + hf * 4;
  unsigned short* outp = Mp + (size_t)(kp * 16 + g6l) * 16384 + hf * 8192 +
                         (size_t)(qp * 64) * 4;
#pragma unroll
  for (int j = 0; j < 8; ++j) {
    int q = qb + j * 8;
    uint2 p = *reinterpret_cast<const uint2*>(&T[q * 132 + kloc]);
    *reinterpret_cast<uint2*>(outp + (size_t)q * 4) = p;
  }
}

// ---------------- NT GEMM: C[M,N] = A[M,K] * B[N,K]^T (+bias) ----------------
template <int WF32, int TN>
__global__ __launch_bounds__(256) void gemm_nt(
    const unsigned short* __restrict__ A, const unsigned short* __restrict__ B0,
    const unsigned short* __restrict__ B1, const unsigned short* __restrict__ B2,
    unsigned short* __restrict__ C0, unsigned short* __restrict__ C1,
    unsigned short* __restrict__ C2, float* __restrict__ Cf,
    const float* __restrict__ bias) {
  constexpr int K = 1024;
  constexpr int NJ = TN / 32;  // per-wave N fragments
  __shared__ unsigned short As[2][128 * 32];
  __shared__ unsigned short Bs[2][TN * 32];
  const int z = blockIdx.z;
  const unsigned short* Bw = (z == 0) ? B0 : (z == 1) ? B1 : B2;
  unsigned short* Cb = (z == 0) ? C0 : (z == 1) ? C1 : C2;
  const int tid = threadIdx.x, lane = tid & 63, wid = tid >> 6;
  const int lr = lane & 15, lk = lane >> 4;
  const int bm = blockIdx.y * 128, bn = blockIdx.x * TN;
  const int wm = (wid >> 1) * 64, wn = (wid & 1) * (TN / 2);
  floatx4 acc[4][NJ] = {};

  const int srow = tid >> 2, scb = (tid & 3) * 16;
  const int ssw = scb ^ (((srow >> 1) & 3) << 4);  // pre-swizzled source col
  const char* gA = (const char*)A + ((size_t)(bm + srow) * K) * 2 + ssw;
  const char* gB = (const char*)Bw + ((size_t)(bn + srow) * K) * 2 + ssw;

  auto stage = [&](int buf, int k0) {
    gload16(gA + (size_t)k0 * 2, (char*)&As[buf][0] + tid * 16);
    gload16(gA + ((size_t)64 * K + k0) * 2, (char*)&As[buf][0] + 4096 + tid * 16);
    gload16(gB + (size_t)k0 * 2, (char*)&Bs[buf][0] + tid * 16);
    if constexpr (TN == 128)
      gload16(gB + ((size_t)64 * K + k0) * 2, (char*)&Bs[buf][0] + 4096 + tid * 16);
  };

  stage(0, 0);
  __syncthreads();
  int cur = 0;
  const int csw = (lk * 16) ^ (((lr >> 1) & 3) << 4);  // read-side swizzle
  for (int k0 = 0; k0 < K; k0 += 32) {
    if (k0 + 32 < K) stage(cur ^ 1, k0 + 32);
    const char* Ab = (const char*)&As[cur][0];
    const char* Bb = (const char*)&Bs[cur][0];
    bfrag8 af[4], bfr[NJ];
#pragma unroll
    for (int i = 0; i < 4; ++i)
      af[i] = *reinterpret_cast<const bfrag8*>(Ab + (wm + i * 16 + lr) * 64 + csw);
#pragma unroll
    for (int j = 0; j < NJ; ++j)
      bfr[j] = *reinterpret_cast<const bfrag8*>(Bb + (wn + j * 16 + lr) * 64 + csw);
#pragma unroll
    for (int i = 0; i < 4; ++i)
#pragma unroll
      for (int j = 0; j < NJ; ++j)
        acc[i][j] = MFMA_BF16(af[i], bfr[j], acc[i][j]);
    __syncthreads();
    cur ^= 1;
  }

#pragma unroll
  for (int i = 0; i < 4; ++i)
#pragma unroll
    for (int j = 0; j < NJ; ++j) {
      const int row = bm + wm + i * 16 + lk * 4;
      const int col = bn + wn + j * 16 + lr;
#pragma unroll
      for (int r = 0; r < 4; ++r) {
        if (WF32)
          Cf[(size_t)(row + r) * D_MODEL + col] = acc[i][j][r] + bias[col];
        else
          Cb[(size_t)(row + r) * D_MODEL + col] = f2bf(acc[i][j][r]);
      }
    }
}

// ---------------- transpose V: [B*S, D] -> Vt[bh][dk][S] ----------------
__global__ __launch_bounds__(256) void transpose_v(
    const unsigned short* __restrict__ V, unsigned short* __restrict__ Vt) {
  __shared__ unsigned short T[64 * 72];
  const int tid = threadIdx.x;
  const int bh = blockIdx.y, s0 = blockIdx.x * 64;
  const int b = bh >> 4, h = bh & 15;
  const unsigned short* src = V + ((size_t)(b * S_LEN + s0)) * D_MODEL + h * DK;
#pragma unroll
  for (int it = 0; it < 2; ++it) {
    int rr = it * 32 + (tid >> 3);
    int cc = (tid & 7) * 8;
    int sw = cc ^ (((rr >> 3) & 7) * 8);
    *reinterpret_cast<uint4*>(&T[rr * 72 + sw]) =
        *reinterpret_cast<const uint4*>(src + (size_t)rr * D_MODEL + cc);
  }
  __syncthreads();
#pragma unroll
  for (int it = 0; it < 2; ++it) {
    int chunk = it * 256 + tid;
    int d = chunk >> 3, sc = chunk & 7;
    unsigned short v[8];
#pragma unroll
    for (int i = 0; i < 8; ++i) {
      int row = sc * 8 + i;
      int col = ((d & ~7) ^ (((row >> 3) & 7) * 8)) + (d & 7);
      v[i] = T[row * 72 + col];
    }
    uint4 pk;
    pk.x = (unsigned int)v[0] | ((unsigned int)v[1] << 16);
    pk.y = (unsigned int)v[2] | ((unsigned int)v[3] << 16);
    pk.z = (unsigned int)v[4] | ((unsigned int)v[5] << 16);
    pk.w = (unsigned int)v[6] | ((unsigned int)v[7] << 16);
    *reinterpret_cast<uint4*>(&Vt[((size_t)bh * DK + d) * S_LEN + s0 + sc * 8]) = pk;
  }
}

// ---------------- fused relu-attention (32x32 MFMA, packed mask) -------------
// Block = one (b,h) x 64 q; 2 waves x 32 q; grid 1024 (4 blocks/CU).
// S^T = mfma32(K,Q); P fully in-register (cvt_pk + permlane32_swap);
// O^T = mfma32(V^T, P^T). Mask read from the packed Mp layout: one uint2 per
// (c,g) group, lanes perfectly coalesced (256B/instr) - no row gather.
__global__ __launch_bounds__(128, 2) void attn_relu(
    const unsigned short* __restrict__ Q, const unsigned short* __restrict__ Kg,
    const unsigned short* __restrict__ Vt, const unsigned short* __restrict__ Mp,
    unsigned short* __restrict__ O) {
  __shared__ unsigned short Kt[2][64 * 64];  // [k][d] 16 KB
  __shared__ unsigned short Vl[2][64 * 64];  // [d][s] 16 KB
  const int tid = threadIdx.x, lane = tid & 63, wid = tid >> 6;  // wid 0..1
  const int lq = lane & 31, hf = lane >> 5;
  // XCD-aware swizzle over 1024 blocks: 128 consecutive flats (4 bh) per XCD.
  int flat = blockIdx.y * 32 + blockIdx.x;
  flat = (flat & 7) * 128 + (flat >> 3);
  const int bh = flat >> 5, q0 = (flat & 31) * 64;
  const int b = bh >> 4, hh = bh & 15;
  const int qg = q0 + wid * 32 + lq;  // this lane's q row

  // Q B-fragments (col=q, k-elems d = ks*16 + hf*8 + i), straight from global
  const unsigned short* qptr = Q + (size_t)(b * S_LEN + qg) * D_MODEL + hh * DK;
  bfrag8 qf[4];
#pragma unroll
  for (int ks = 0; ks < 4; ++ks)
    qf[ks] = *reinterpret_cast<const bfrag8*>(qptr + ks * 16 + hf * 8);

  // staging: 128 threads; thread t -> tile row p*16 + (t>>3), chunk (t&7)*16
  const int srow = tid >> 3, scb = (tid & 7) * 16;
  const int ssw = scb ^ ((srow & 7) << 4) ^ (((srow >> 3) & 1) << 5);
  const char* kg = (const char*)Kg + ((size_t)(b * S_LEN + srow)) * 2048 + hh * 128 + ssw;
  const char* vg = (const char*)Vt + (size_t)bh * (DK * S_LEN * 2) +
                   (size_t)srow * (S_LEN * 2) + ssw;
  // packed mask base for this lane
  const unsigned short* mpb = Mp + (size_t)hf * 8192 + (size_t)qg * 4;
  const int swzr = ((lq & 7) << 4) ^ (((lq >> 3) & 1) << 5);  // read-side

  floatx16 oacc[2] = {};

  auto stage = [&](int buf, int kt) {
#pragma unroll
    for (int p = 0; p < 4; ++p) {
      gload16(kg + (size_t)(kt * 64 + p * 16) * 2048,
              (char*)&Kt[buf][0] + p * 2048 + tid * 16);
      gload16(vg + (size_t)(p * 16) * 4096 + (size_t)kt * 128,
              (char*)&Vl[buf][0] + p * 2048 + tid * 16);
    }
  };

  stage(0, 0);
  __syncthreads();

  int cur = 0;
  constexpr int NT = S_LEN / 64;
  for (int kt = 0; kt < NT; ++kt) {
    if (kt + 1 < NT) stage(cur ^ 1, kt + 1);
    // mask fragments: one coalesced uint2 per (c,g); g6 = kt*8 + c*4 + g
    uint2 mk[2][4];
#pragma unroll
    for (int c = 0; c < 2; ++c)
#pragma unroll
      for (int g = 0; g < 4; ++g)
        mk[c][g] = *reinterpret_cast<const uint2*>(
            mpb + (size_t)(kt * 8 + c * 4 + g) * 16384);

    // ---- scores: sacc[c] = S^T (32k x 32q), c = k-block
    const char* Kb = (const char*)&Kt[cur][0];
    floatx16 sacc[2] = {};
    __builtin_amdgcn_s_setprio(1);
#pragma unroll
    for (int c = 0; c < 2; ++c)
#pragma unroll
      for (int ks = 0; ks < 4; ++ks) {
        bfrag8 kf = *reinterpret_cast<const bfrag8*>(
            Kb + (c * 32 + lq) * 128 + (((ks * 16 + hf * 8) * 2) ^ swzr));
        sacc[c] = MFMA32(kf, qf[ks], sacc[c]);
      }
    __builtin_amdgcn_s_setprio(0);

    // ---- relu(scale*s + mask) in registers -> bf16 -> permlane32_swap
    bfrag8 pf[4];
#pragma unroll
    for (int c = 0; c < 2; ++c) {
      float p[16];
#pragma unroll
      for (int g = 0; g < 4; ++g) {
        float m0 = __uint_as_float((mk[c][g].x & 0xffffu) << 16);
        float m1 = __uint_as_float(mk[c][g].x & 0xffff0000u);
        float m2 = __uint_as_float((mk[c][g].y & 0xffffu) << 16);
        float m3 = __uint_as_float(mk[c][g].y & 0xffff0000u);
        p[4 * g + 0] = fmaxf(fmaf(sacc[c][4 * g + 0], 0.125f, m0), 0.f);
        p[4 * g + 1] = fmaxf(fmaf(sacc[c][4 * g + 1], 0.125f, m1), 0.f);
        p[4 * g + 2] = fmaxf(fmaf(sacc[c][4 * g + 2], 0.125f, m2), 0.f);
        p[4 * g + 3] = fmaxf(fmaf(sacc[c][4 * g + 3], 0.125f, m3), 0.f);
      }
      unsigned int a0, a1, b0, b1, a2, a3, b2, b3;
      asm("v_cvt_pk_bf16_f32 %0, %1, %2" : "=v"(a0) : "v"(p[0]), "v"(p[1]));
      asm("v_cvt_pk_bf16_f32 %0, %1, %2" : "=v"(a1) : "v"(p[2]), "v"(p[3]));
      asm("v_cvt_pk_bf16_f32 %0, %1, %2" : "=v"(b0) : "v"(p[4]), "v"(p[5]));
      asm("v_cvt_pk_bf16_f32 %0, %1, %2" : "=v"(b1) : "v"(p[6]), "v"(p[7]));
      asm("v_cvt_pk_bf16_f32 %0, %1, %2" : "=v"(a2) : "v"(p[8]), "v"(p[9]));
      asm("v_cvt_pk_bf16_f32 %0, %1, %2" : "=v"(a3) : "v"(p[10]), "v"(p[11]));
      asm("v_cvt_pk_bf16_f32 %0, %1, %2" : "=v"(b2) : "v"(p[12]), "v"(p[13]));
      asm("v_cvt_pk_bf16_f32 %0, %1, %2" : "=v"(b3) : "v"(p[14]), "v"(p[15]));
      asm("v_permlane32_swap_b32 %0, %1" : "+v"(a0), "+v"(b0));
      asm("v_permlane32_swap_b32 %0, %1" : "+v"(a1), "+v"(b1));
      asm("v_permlane32_swap_b32 %0, %1" : "+v"(a2), "+v"(b2));
      asm("v_permlane32_swap_b32 %0, %1" : "+v"(a3), "+v"(b3));
      uint4 u0, u1;
      u0.x = a0; u0.y = a1; u0.z = b0; u0.w = b1;  // k-step c*2+0
      u1.x = a2; u1.y = a3; u1.z = b2; u1.w = b3;  // k-step c*2+1
      pf[c * 2 + 0] = *reinterpret_cast<bfrag8*>(&u0);
      pf[c * 2 + 1] = *reinterpret_cast<bfrag8*>(&u1);
    }

    // ---- PV: O^T += mfma32(A = V^T frag from LDS, B = P^T frag in regs)
    const char* Vb = (const char*)&Vl[cur][0];
    __builtin_amdgcn_s_setprio(1);
#pragma unroll
    for (int d = 0; d < 2; ++d)
#pragma unroll
      for (int s = 0; s < 4; ++s) {
        bfrag8 vb = *reinterpret_cast<const bfrag8*>(
            Vb + (d * 32 + lq) * 128 + (((s * 16 + hf * 8) * 2) ^ swzr));
        oacc[d] = MFMA32(vb, pf[s], oacc[d]);
      }
    __builtin_amdgcn_s_setprio(0);
    __syncthreads();  // prefetch landed; both waves done with cur
    cur ^= 1;
  }

  // ---- write O (bf16, [B*S][D]); O^T row d = dblk*32 + (reg&3)+8g+4hf, col q
  const size_t obase = (size_t)(b * S_LEN + qg) * D_MODEL + hh * DK;
#pragma unroll
  for (int d = 0; d < 2; ++d)
#pragma unroll
    for (int g = 0; g < 4; ++g) {
      uint2 pk;
      pk.x = (unsigned int)f2bf(oacc[d][4 * g + 0]) |
             ((unsigned int)f2bf(oacc[d][4 * g + 1]) << 16);
      pk.y = (unsigned int)f2bf(oacc[d][4 * g + 2]) |
             ((unsigned int)f2bf(oacc[d][4 * g + 3]) << 16);
      *reinterpret_cast<uint2*>(&O[obase + d * 32 + 8 * g + 4 * hf]) = pk;
    }
}

extern "C" void kernel_launch(void* const* d_in, const int* in_sizes, int n_in,
                              void* d_out, int out_size, void* d_ws, size_t ws_size,
                              hipStream_t stream) {
  const float* x = (const float*)d_in[0];
  const float* mask = (const float*)d_in[1];
  const float* Wq = (const float*)d_in[2];
  const float* Wk = (const float*)d_in[3];
  const float* Wv = (const float*)d_in[4];
  const float* Wfc = (const float*)d_in[5];
  const float* bfc = (const float*)d_in[6];
  float* out = (float*)d_out;

  char* ws = (char*)d_ws;
  const size_t MB = 1u << 20;
  unsigned short* xb = (unsigned short*)(ws + 0 * MB);     // 8 MB (reused as Ow)
  unsigned short* Wqb = (unsigned short*)(ws + 8 * MB);    // 2 MB
  unsigned short* Wkb = (unsigned short*)(ws + 10 * MB);   // 2 MB
  unsigned short* Wvb = (unsigned short*)(ws + 12 * MB);   // 2 MB
  unsigned short* Wfb = (unsigned short*)(ws + 14 * MB);   // 2 MB
  unsigned short* Qw = (unsigned short*)(ws + 16 * MB);    // 8 MB
  unsigned short* Kw = (unsigned short*)(ws + 24 * MB);    // 8 MB
  unsigned short* Vw = (unsigned short*)(ws + 32 * MB);    // 8 MB
  unsigned short* Vtw = (unsigned short*)(ws + 40 * MB);   // 8 MB
  unsigned short* Mpw = (unsigned short*)(ws + 48 * MB);   // 8 MB packed mask
  unsigned short* Ow = xb;  // attn runs after QKV GEMMs; xb is dead by then

  cvt_all<<<8192, 256, 0, stream>>>(x, Wq, Wk, Wv, Wfc,
                                    xb, Wqb, Wkb, Wvb, Wfb);
  pack_mask<<<dim3(16, 32), 256, 0, stream>>>(mask, Mpw);

  // merged Q/K/V projection: one launch, z selects weight/output
  gemm_nt<0, 128><<<dim3(D_MODEL / 128, (2 * S_LEN) / 128, 3), 256, 0, stream>>>(
      xb, Wqb, Wkb, Wvb, Qw, Kw, Vw, nullptr, nullptr);

  transpose_v<<<dim3(S_LEN / 64, 32), 256, 0, stream>>>(Vw, Vtw);

  attn_relu<<<dim3(S_LEN / 64, 32), 128, 0, stream>>>(Qw, Kw, Vtw, Mpw, Ow);

  // FC: 128x64 tiles -> 512 blocks (2/CU) for latency hiding
  gemm_nt<1, 64><<<dim3(D_MODEL / 64, (2 * S_LEN) / 128, 1), 256, 0, stream>>>(
      Ow, Wfb, nullptr, nullptr, nullptr, nullptr, nullptr, out, bfc);
}

// Round 9
// 132.450 us; speedup vs baseline: 1.9280x; 1.0376x over previous
//
#include <hip/hip_runtime.h>

typedef short bfrag8 __attribute__((ext_vector_type(8)));
typedef float floatx4 __attribute__((ext_vector_type(4)));
typedef float floatx16 __attribute__((ext_vector_type(16)));

#define MFMA_BF16(a, b, c) __builtin_amdgcn_mfma_f32_16x16x32_bf16((a), (b), (c), 0, 0, 0)
#define MFMA32(a, b, c) __builtin_amdgcn_mfma_f32_32x32x16_bf16((a), (b), (c), 0, 0, 0)

#define S_LEN 2048
#define D_MODEL 1024
#define NH 16
#define DK 64

__device__ __forceinline__ unsigned short f2bf(float f) {
  unsigned int u = __float_as_uint(f);
  u += 0x7fffu + ((u >> 16) & 1u);
  return (unsigned short)(u >> 16);
}

typedef const __attribute__((address_space(1))) unsigned int guint;
typedef __attribute__((address_space(3))) unsigned int luint;
__device__ __forceinline__ void gload16(const void* g, void* l) {
  __builtin_amdgcn_global_load_lds((guint*)g, (luint*)l, 16, 0, 0);
}

// ---------------- f32 -> bf16 conversions (x + 4 weights) ----------------
// regions (in 1024-elt blocks): x 4096 | wq wk wv wfc 1024 each.
// Wq is pre-scaled by 0.125 (1/sqrt(dk)) - exact power of 2, bit-identical
// to applying the scale to S later; removes the scale from the attn epilogue.
__global__ __launch_bounds__(256) void cvt_all(
    const float* __restrict__ x, const float* __restrict__ wq,
    const float* __restrict__ wk, const float* __restrict__ wv,
    const float* __restrict__ wfc, unsigned short* __restrict__ xb,
    unsigned short* __restrict__ wqb, unsigned short* __restrict__ wkb,
    unsigned short* __restrict__ wvb, unsigned short* __restrict__ wfb) {
  const int bid = blockIdx.x;
  const float* src;
  unsigned short* dst;
  int base;
  float sc = 1.0f;
  if (bid < 4096) { src = x; dst = xb; base = bid; }
  else if (bid < 5120) { src = wq; dst = wqb; base = bid - 4096; sc = 0.125f; }
  else if (bid < 6144) { src = wk; dst = wkb; base = bid - 5120; }
  else if (bid < 7168) { src = wv; dst = wvb; base = bid - 6144; }
  else { src = wfc; dst = wfb; base = bid - 7168; }
  const int i = (base * 256 + threadIdx.x) * 4;
  float4 v = *reinterpret_cast<const float4*>(src + i);
  v.x *= sc; v.y *= sc; v.z *= sc; v.w *= sc;
  uint2 p;
  p.x = (unsigned int)f2bf(v.x) | ((unsigned int)f2bf(v.y) << 16);
  p.y = (unsigned int)f2bf(v.z) | ((unsigned int)f2bf(v.w) << 16);
  *reinterpret_cast<uint2*>(dst + i) = p;
}

// ---------------- pack mask into MFMA-fragment order ----------------
// Mp layout: [g6 = k>>3][hf = (k>>2)&1][q][r = k&3] bf16: a lane's 4 k-values
// for its (c,g,hf) group are one uint2 at elem offset ((g6*2+hf)*2048 + q)*4.
__global__ __launch_bounds__(256) void pack_mask(
    const float* __restrict__ mask, unsigned short* __restrict__ Mp) {
  __shared__ unsigned short T[64 * 132];
  const int tid = threadIdx.x;
  const int kp = blockIdx.x, qp = blockIdx.y;  // 128-k patch, 64-q patch
#pragma unroll
  for (int it = 0; it < 8; ++it) {
    int idx = it * 256 + tid;
    int q = idx >> 5, kq = (idx & 31) * 4;
    float4 v = *reinterpret_cast<const float4*>(
        mask + (size_t)(qp * 64 + q) * 2048 + kp * 128 + kq);
    uint2 p;
    p.x = (unsigned int)f2bf(v.x) | ((unsigned int)f2bf(v.y) << 16);
    p.y = (unsigned int)f2bf(v.z) | ((unsigned int)f2bf(v.w) << 16);
    *reinterpret_cast<uint2*>(&T[q * 132 + kq]) = p;
  }
  __syncthreads();
  const int run = tid >> 3, qb = tid & 7;   // 32 runs x 8 q-lanes
  const int g6l = run >> 1, hf = run & 1;   // local k-group, half
  const int kloc = g6l * 8 + hf * 4;
  unsigned short* outp = Mp + (size_t)(kp * 16 + g6l) * 16384 + hf * 8192 +
                         (size_t)(qp * 64) * 4;
#pragma unroll
  for (int j = 0; j < 8; ++j) {
    int q = qb + j * 8;
    uint2 p = *reinterpret_cast<const uint2*>(&T[q * 132 + kloc]);
    *reinterpret_cast<uint2*>(outp + (size_t)q * 4) = p;
  }
}

// ---------------- NT GEMM: C[M,N] = A[M,K] * B[N,K]^T (+bias) ----------------
template <int WF32, int TN>
__global__ __launch_bounds__(256) void gemm_nt(
    const unsigned short* __restrict__ A, const unsigned short* __restrict__ B0,
    const unsigned short* __restrict__ B1, const unsigned short* __restrict__ B2,
    unsigned short* __restrict__ C0, unsigned short* __restrict__ C1,
    unsigned short* __restrict__ C2, float* __restrict__ Cf,
    const float* __restrict__ bias) {
  constexpr int K = 1024;
  constexpr int NJ = TN / 32;  // per-wave N fragments
  __shared__ unsigned short As[2][128 * 32];
  __shared__ unsigned short Bs[2][TN * 32];
  const int z = blockIdx.z;
  const unsigned short* Bw = (z == 0) ? B0 : (z == 1) ? B1 : B2;
  unsigned short* Cb = (z == 0) ? C0 : (z == 1) ? C1 : C2;
  const int tid = threadIdx.x, lane = tid & 63, wid = tid >> 6;
  const int lr = lane & 15, lk = lane >> 4;
  const int bm = blockIdx.y * 128, bn = blockIdx.x * TN;
  const int wm = (wid >> 1) * 64, wn = (wid & 1) * (TN / 2);
  floatx4 acc[4][NJ] = {};

  const int srow = tid >> 2, scb = (tid & 3) * 16;
  const int ssw = scb ^ (((srow >> 1) & 3) << 4);  // pre-swizzled source col
  const char* gA = (const char*)A + ((size_t)(bm + srow) * K) * 2 + ssw;
  const char* gB = (const char*)Bw + ((size_t)(bn + srow) * K) * 2 + ssw;

  auto stage = [&](int buf, int k0) {
    gload16(gA + (size_t)k0 * 2, (char*)&As[buf][0] + tid * 16);
    gload16(gA + ((size_t)64 * K + k0) * 2, (char*)&As[buf][0] + 4096 + tid * 16);
    gload16(gB + (size_t)k0 * 2, (char*)&Bs[buf][0] + tid * 16);
    if constexpr (TN == 128)
      gload16(gB + ((size_t)64 * K + k0) * 2, (char*)&Bs[buf][0] + 4096 + tid * 16);
  };

  stage(0, 0);
  __syncthreads();
  int cur = 0;
  const int csw = (lk * 16) ^ (((lr >> 1) & 3) << 4);  // read-side swizzle
  for (int k0 = 0; k0 < K; k0 += 32) {
    if (k0 + 32 < K) stage(cur ^ 1, k0 + 32);
    const char* Ab = (const char*)&As[cur][0];
    const char* Bb = (const char*)&Bs[cur][0];
    bfrag8 af[4], bfr[NJ];
#pragma unroll
    for (int i = 0; i < 4; ++i)
      af[i] = *reinterpret_cast<const bfrag8*>(Ab + (wm + i * 16 + lr) * 64 + csw);
#pragma unroll
    for (int j = 0; j < NJ; ++j)
      bfr[j] = *reinterpret_cast<const bfrag8*>(Bb + (wn + j * 16 + lr) * 64 + csw);
#pragma unroll
    for (int i = 0; i < 4; ++i)
#pragma unroll
      for (int j = 0; j < NJ; ++j)
        acc[i][j] = MFMA_BF16(af[i], bfr[j], acc[i][j]);
    __syncthreads();
    cur ^= 1;
  }

#pragma unroll
  for (int i = 0; i < 4; ++i)
#pragma unroll
    for (int j = 0; j < NJ; ++j) {
      const int row = bm + wm + i * 16 + lk * 4;
      const int col = bn + wn + j * 16 + lr;
#pragma unroll
      for (int r = 0; r < 4; ++r) {
        if (WF32)
          Cf[(size_t)(row + r) * D_MODEL + col] = acc[i][j][r] + bias[col];
        else
          Cb[(size_t)(row + r) * D_MODEL + col] = f2bf(acc[i][j][r]);
      }
    }
}

// ---------------- transpose V: [B*S, D] -> Vt[bh][dk][S] ----------------
__global__ __launch_bounds__(256) void transpose_v(
    const unsigned short* __restrict__ V, unsigned short* __restrict__ Vt) {
  __shared__ unsigned short T[64 * 72];
  const int tid = threadIdx.x;
  const int bh = blockIdx.y, s0 = blockIdx.x * 64;
  const int b = bh >> 4, h = bh & 15;
  const unsigned short* src = V + ((size_t)(b * S_LEN + s0)) * D_MODEL + h * DK;
#pragma unroll
  for (int it = 0; it < 2; ++it) {
    int rr = it * 32 + (tid >> 3);
    int cc = (tid & 7) * 8;
    int sw = cc ^ (((rr >> 3) & 7) * 8);
    *reinterpret_cast<uint4*>(&T[rr * 72 + sw]) =
        *reinterpret_cast<const uint4*>(src + (size_t)rr * D_MODEL + cc);
  }
  __syncthreads();
#pragma unroll
  for (int it = 0; it < 2; ++it) {
    int chunk = it * 256 + tid;
    int d = chunk >> 3, sc = chunk & 7;
    unsigned short v[8];
#pragma unroll
    for (int i = 0; i < 8; ++i) {
      int row = sc * 8 + i;
      int col = ((d & ~7) ^ (((row >> 3) & 7) * 8)) + (d & 7);
      v[i] = T[row * 72 + col];
    }
    uint4 pk;
    pk.x = (unsigned int)v[0] | ((unsigned int)v[1] << 16);
    pk.y = (unsigned int)v[2] | ((unsigned int)v[3] << 16);
    pk.z = (unsigned int)v[4] | ((unsigned int)v[5] << 16);
    pk.w = (unsigned int)v[6] | ((unsigned int)v[7] << 16);
    *reinterpret_cast<uint4*>(&Vt[((size_t)bh * DK + d) * S_LEN + s0 + sc * 8]) = pk;
  }
}

// ---------------- fused relu-attention (k-split waves, mask as MFMA C) -------
// Block = one (b,h) x 64 q; 4 waves = 2 q-groups x 2 k-halves (c). Grid 1024
// (4 blocks/CU, 16 waves/CU). Wave (qgrp,c): S^T(c-half) = mfma32(K,Q) with
// C initialized to the mask fragment (scale pre-folded into Wq); epilogue is
// just relu + cvt_pk + permlane32_swap (P in registers); partial O^T over the
// c-half accumulates in regs; the two c-halves are summed once at the end via
// a stride-66 (2-way-conflict-free) LDS exchange.
__global__ __launch_bounds__(256, 4) void attn_relu(
    const unsigned short* __restrict__ Q, const unsigned short* __restrict__ Kg,
    const unsigned short* __restrict__ Vt, const unsigned short* __restrict__ Mp,
    unsigned short* __restrict__ O) {
  __shared__ unsigned short KV[2][2][64 * 64];  // [buf][0=K,1=V] 32 KB
  const int tid = threadIdx.x, lane = tid & 63, wid = tid >> 6;
  const int lq = lane & 31, hf = lane >> 5;
  const int qgrp = wid >> 1, cn = wid & 1;
  // XCD-aware swizzle over 1024 blocks: 128 consecutive flats (4 bh) per XCD.
  int flat = blockIdx.y * 32 + blockIdx.x;
  flat = (flat & 7) * 128 + (flat >> 3);
  const int bh = flat >> 5, q0 = (flat & 31) * 64;
  const int b = bh >> 4, hh = bh & 15;
  const int qg = q0 + qgrp * 32 + lq;  // this lane's q row

  // Q B-fragments (col=q, k-elems d = ks*16 + hf*8 + i), straight from global
  const unsigned short* qptr = Q + (size_t)(b * S_LEN + qg) * D_MODEL + hh * DK;
  bfrag8 qf[4];
#pragma unroll
  for (int ks = 0; ks < 4; ++ks)
    qf[ks] = *reinterpret_cast<const bfrag8*>(qptr + ks * 16 + hf * 8);

  // staging: 256 threads; thread t -> tile row p*32 + (t>>3), chunk (t&7)*16
  const int srow = tid >> 3, scb = (tid & 7) * 16;
  const int ssw = scb ^ ((srow & 7) << 4) ^ (((srow >> 3) & 1) << 5);
  const char* kg = (const char*)Kg + ((size_t)(b * S_LEN + srow)) * 2048 + hh * 128 + ssw;
  const char* vg = (const char*)Vt + (size_t)bh * (DK * S_LEN * 2) +
                   (size_t)srow * (S_LEN * 2) + ssw;
  const unsigned short* mpb = Mp + (size_t)hf * 8192 + (size_t)qg * 4;
  const int swzr = ((lq & 7) << 4) ^ (((lq >> 3) & 1) << 5);  // read-side

  floatx16 oacc[2] = {};

  auto stage = [&](int buf, int kt) {
#pragma unroll
    for (int p = 0; p < 2; ++p) {
      gload16(kg + (size_t)(kt * 64 + p * 32) * 2048,
              (char*)&KV[buf][0][0] + p * 4096 + tid * 16);
      gload16(vg + (size_t)(p * 32) * 4096 + (size_t)kt * 128,
              (char*)&KV[buf][1][0] + p * 4096 + tid * 16);
    }
  };

  stage(0, 0);
  __syncthreads();

  int cur = 0;
  constexpr int NT = S_LEN / 64;
  for (int kt = 0; kt < NT; ++kt) {
    if (kt + 1 < NT) stage(cur ^ 1, kt + 1);
    // mask fragment for this wave's c-half; g6 = kt*8 + cn*4 + g
    uint2 mk[4];
#pragma unroll
    for (int g = 0; g < 4; ++g)
      mk[g] = *reinterpret_cast<const uint2*>(
          mpb + (size_t)(kt * 8 + cn * 4 + g) * 16384);

    // ---- S^T = mask + K^T Q (mask as MFMA C-init; scale folded into Q)
    floatx16 sacc;
#pragma unroll
    for (int g = 0; g < 4; ++g) {
      sacc[4 * g + 0] = __uint_as_float((mk[g].x & 0xffffu) << 16);
      sacc[4 * g + 1] = __uint_as_float(mk[g].x & 0xffff0000u);
      sacc[4 * g + 2] = __uint_as_float((mk[g].y & 0xffffu) << 16);
      sacc[4 * g + 3] = __uint_as_float(mk[g].y & 0xffff0000u);
    }
    const char* Kb = (const char*)&KV[cur][0][0];
    __builtin_amdgcn_s_setprio(1);
#pragma unroll
    for (int ks = 0; ks < 4; ++ks) {
      bfrag8 kf = *reinterpret_cast<const bfrag8*>(
          Kb + (cn * 32 + lq) * 128 + (((ks * 16 + hf * 8) * 2) ^ swzr));
      sacc = MFMA32(kf, qf[ks], sacc);
    }
    __builtin_amdgcn_s_setprio(0);

    // ---- relu -> bf16 -> permlane32_swap (P fully in registers)
    float p[16];
#pragma unroll
    for (int i = 0; i < 16; ++i) p[i] = fmaxf(sacc[i], 0.f);
    unsigned int a0, a1, b0, b1, a2, a3, b2, b3;
    asm("v_cvt_pk_bf16_f32 %0, %1, %2" : "=v"(a0) : "v"(p[0]), "v"(p[1]));
    asm("v_cvt_pk_bf16_f32 %0, %1, %2" : "=v"(a1) : "v"(p[2]), "v"(p[3]));
    asm("v_cvt_pk_bf16_f32 %0, %1, %2" : "=v"(b0) : "v"(p[4]), "v"(p[5]));
    asm("v_cvt_pk_bf16_f32 %0, %1, %2" : "=v"(b1) : "v"(p[6]), "v"(p[7]));
    asm("v_cvt_pk_bf16_f32 %0, %1, %2" : "=v"(a2) : "v"(p[8]), "v"(p[9]));
    asm("v_cvt_pk_bf16_f32 %0, %1, %2" : "=v"(a3) : "v"(p[10]), "v"(p[11]));
    asm("v_cvt_pk_bf16_f32 %0, %1, %2" : "=v"(b2) : "v"(p[12]), "v"(p[13]));
    asm("v_cvt_pk_bf16_f32 %0, %1, %2" : "=v"(b3) : "v"(p[14]), "v"(p[15]));
    asm("v_permlane32_swap_b32 %0, %1" : "+v"(a0), "+v"(b0));
    asm("v_permlane32_swap_b32 %0, %1" : "+v"(a1), "+v"(b1));
    asm("v_permlane32_swap_b32 %0, %1" : "+v"(a2), "+v"(b2));
    asm("v_permlane32_swap_b32 %0, %1" : "+v"(a3), "+v"(b3));
    uint4 u0, u1;
    u0.x = a0; u0.y = a1; u0.z = b0; u0.w = b1;  // local k-step 0
    u1.x = a2; u1.y = a3; u1.z = b2; u1.w = b3;  // local k-step 1
    bfrag8 pf0 = *reinterpret_cast<bfrag8*>(&u0);
    bfrag8 pf1 = *reinterpret_cast<bfrag8*>(&u1);

    // ---- partial PV over this wave's k-half: global s = cn*2 + sl
    const char* Vb = (const char*)&KV[cur][1][0];
    __builtin_amdgcn_s_setprio(1);
#pragma unroll
    for (int d = 0; d < 2; ++d) {
      bfrag8 vb0 = *reinterpret_cast<const bfrag8*>(
          Vb + (d * 32 + lq) * 128 + ((((cn * 2 + 0) * 16 + hf * 8) * 2) ^ swzr));
      oacc[d] = MFMA32(vb0, pf0, oacc[d]);
      bfrag8 vb1 = *reinterpret_cast<const bfrag8*>(
          Vb + (d * 32 + lq) * 128 + ((((cn * 2 + 1) * 16 + hf * 8) * 2) ^ swzr));
      oacc[d] = MFMA32(vb1, pf1, oacc[d]);
    }
    __builtin_amdgcn_s_setprio(0);
    __syncthreads();  // prefetch landed; all waves done with cur
    cur ^= 1;
  }

  // ---- combine the two k-halves: c=1 waves export via LDS (stride 66 f32 ->
  // bank stride 2 -> 2-way conflict = free), c=0 waves add and write O.
  float* X = (float*)&KV[0][0][0];  // 64 rows x 66 f32 = 16.9 KB < 32 KB
  const int xrow = (qgrp * 32 + lq) * 66;
  if (cn == 1) {
#pragma unroll
    for (int d = 0; d < 2; ++d)
#pragma unroll
      for (int g = 0; g < 4; ++g) {
        const int off = xrow + d * 32 + 8 * g + 4 * hf;
        float2 lo, hi;
        lo.x = oacc[d][4 * g + 0]; lo.y = oacc[d][4 * g + 1];
        hi.x = oacc[d][4 * g + 2]; hi.y = oacc[d][4 * g + 3];
        *reinterpret_cast<float2*>(&X[off]) = lo;
        *reinterpret_cast<float2*>(&X[off + 2]) = hi;
      }
  }
  __syncthreads();
  if (cn == 0) {
    const size_t obase = (size_t)(b * S_LEN + qg) * D_MODEL + hh * DK;
#pragma unroll
    for (int d = 0; d < 2; ++d)
#pragma unroll
      for (int g = 0; g < 4; ++g) {
        const int off = xrow + d * 32 + 8 * g + 4 * hf;
        float2 lo = *reinterpret_cast<const float2*>(&X[off]);
        float2 hi = *reinterpret_cast<const float2*>(&X[off + 2]);
        float o0 = oacc[d][4 * g + 0] + lo.x;
        float o1 = oacc[d][4 * g + 1] + lo.y;
        float o2 = oacc[d][4 * g + 2] + hi.x;
        float o3 = oacc[d][4 * g + 3] + hi.y;
        uint2 pk;
        pk.x = (unsigned int)f2bf(o0) | ((unsigned int)f2bf(o1) << 16);
        pk.y = (unsigned int)f2bf(o2) | ((unsigned int)f2bf(o3) << 16);
        *reinterpret_cast<uint2*>(&O[obase + d * 32 + 8 * g + 4 * hf]) = pk;
      }
  }
}

extern "C" void kernel_launch(void* const* d_in, const int* in_sizes, int n_in,
                              void* d_out, int out_size, void* d_ws, size_t ws_size,
                              hipStream_t stream) {
  const float* x = (const float*)d_in[0];
  const float* mask = (const float*)d_in[1];
  const float* Wq = (const float*)d_in[2];
  const float* Wk = (const float*)d_in[3];
  const float* Wv = (const float*)d_in[4];
  const float* Wfc = (const float*)d_in[5];
  const float* bfc = (const float*)d_in[6];
  float* out = (float*)d_out;

  char* ws = (char*)d_ws;
  const size_t MB = 1u << 20;
  unsigned short* xb = (unsigned short*)(ws + 0 * MB);     // 8 MB (reused as Ow)
  unsigned short* Wqb = (unsigned short*)(ws + 8 * MB);    // 2 MB
  unsigned short* Wkb = (unsigned short*)(ws + 10 * MB);   // 2 MB
  unsigned short* Wvb = (unsigned short*)(ws + 12 * MB);   // 2 MB
  unsigned short* Wfb = (unsigned short*)(ws + 14 * MB);   // 2 MB
  unsigned short* Qw = (unsigned short*)(ws + 16 * MB);    // 8 MB
  unsigned short* Kw = (unsigned short*)(ws + 24 * MB);    // 8 MB
  unsigned short* Vw = (unsigned short*)(ws + 32 * MB);    // 8 MB
  unsigned short* Vtw = (unsigned short*)(ws + 40 * MB);   // 8 MB
  unsigned short* Mpw = (unsigned short*)(ws + 48 * MB);   // 8 MB packed mask
  unsigned short* Ow = xb;  // attn runs after QKV GEMMs; xb is dead by then

  cvt_all<<<8192, 256, 0, stream>>>(x, Wq, Wk, Wv, Wfc,
                                    xb, Wqb, Wkb, Wvb, Wfb);
  pack_mask<<<dim3(16, 32), 256, 0, stream>>>(mask, Mpw);

  // merged Q/K/V projection: one launch, z selects weight/output
  gemm_nt<0, 128><<<dim3(D_MODEL / 128, (2 * S_LEN) / 128, 3), 256, 0, stream>>>(
      xb, Wqb, Wkb, Wvb, Qw, Kw, Vw, nullptr, nullptr);

  transpose_v<<<dim3(S_LEN / 64, 32), 256, 0, stream>>>(Vw, Vtw);

  attn_relu<<<dim3(S_LEN / 64, 32), 256, 0, stream>>>(Qw, Kw, Vtw, Mpw, Ow);

  // FC: 128x64 tiles -> 512 blocks (2/CU) for latency hiding
  gemm_nt<1, 64><<<dim3(D_MODEL / 64, (2 * S_LEN) / 128, 1), 256, 0, stream>>>(
      Ow, Wfb, nullptr, nullptr, nullptr, nullptr, nullptr, out, bfc);
}